// Round 9
// baseline (985.743 us; speedup 1.0000x reference)
//
#include <hip/hip_runtime.h>
#include <cfloat>
#include <cmath>

// NoisyTopKRouter eval-mode: logits = x @ W^T, top-2 + softmax over top-2.
// N=131072, D=2048, E=16. Outputs (concatenated flat in d_out as float32):
//   [0 .. 2N)   topk indices (as float values; ref dtype int64)
//   [2N .. 4N)  gating weights (softmax over the two top logits)
//
// BIT-EXACTNESS (round 7 lesson): each (row, expert) dot computed by ONE
// lane over all of D, 4 mod-4 fma chains ascending, reduced (c0+c1)+(c2+c3).
//
// No-LDS register-streaming design (round 8 lesson: the LDS round-trip's DS
// pipe cost ~= the whole HBM budget):
//   lane = (eq = lane>>4: expert-quad, r = lane&15: row). Lane streams its
//   own x row from global in 128 B line-complete unroll bodies (8 x float4);
//   the 4 eq-groups' duplicate addresses dedup in the coalescer, so x is
//   fetched exactly once. W (128 KB, L1/L2-hot) loaded 4 float4 per j-step,
//   uniform across each 16-lane group. Zero LDS, zero barriers, zero ds ops.
//   acc = 4 experts x float4 = 16 VGPRs; ~100 VGPRs total under the 128 cap.

constexpr int D = 2048;
constexpr int E = 16;
constexpr int BLOCK = 256;           // 4 waves
constexpr int RPW = 16;              // rows per wave
constexpr int RB  = 4 * RPW;         // 64 rows per block
constexpr int NC  = D / 32;          // 64 cache lines (128 B) per row

__global__ __launch_bounds__(BLOCK, 2) void router_kernel(
    const float* __restrict__ x, const float* __restrict__ W,
    float* __restrict__ out, int N) {
  const int tid  = threadIdx.x;
  const int lane = tid & 63;
  const int wid  = tid >> 6;         // 0..3
  const int r    = lane & 15;        // row owned by this lane
  const int eq   = lane >> 4;        // expert quad: experts 4eq..4eq+3
  const int row  = blockIdx.x * RB + wid * RPW + r;
  if (row >= N) return;

  const float* __restrict__ xr = x + (size_t)row * D;
  const float* __restrict__ wq = W + (size_t)(4 * eq) * D;

  // acc[e] = mod-4 chains for expert 4eq+e of this row
  float4 a0 = make_float4(0.f, 0.f, 0.f, 0.f), a1 = a0, a2 = a0, a3 = a0;

  #pragma unroll 2
  for (int c = 0; c < NC; ++c) {     // one 128 B line of the row per iter
    float4 xv[8];
    #pragma unroll
    for (int j = 0; j < 8; ++j)
      xv[j] = *reinterpret_cast<const float4*>(xr + c * 32 + 4 * j);
    #pragma unroll
    for (int j = 0; j < 8; ++j) {
      const int off = c * 32 + 4 * j;
      const float4 w0 = *reinterpret_cast<const float4*>(wq + off);
      const float4 w1 = *reinterpret_cast<const float4*>(wq + D + off);
      const float4 w2 = *reinterpret_cast<const float4*>(wq + 2 * D + off);
      const float4 w3 = *reinterpret_cast<const float4*>(wq + 3 * D + off);
      a0.x = fmaf(xv[j].x, w0.x, a0.x); a0.y = fmaf(xv[j].y, w0.y, a0.y);
      a0.z = fmaf(xv[j].z, w0.z, a0.z); a0.w = fmaf(xv[j].w, w0.w, a0.w);
      a1.x = fmaf(xv[j].x, w1.x, a1.x); a1.y = fmaf(xv[j].y, w1.y, a1.y);
      a1.z = fmaf(xv[j].z, w1.z, a1.z); a1.w = fmaf(xv[j].w, w1.w, a1.w);
      a2.x = fmaf(xv[j].x, w2.x, a2.x); a2.y = fmaf(xv[j].y, w2.y, a2.y);
      a2.z = fmaf(xv[j].z, w2.z, a2.z); a2.w = fmaf(xv[j].w, w2.w, a2.w);
      a3.x = fmaf(xv[j].x, w3.x, a3.x); a3.y = fmaf(xv[j].y, w3.y, a3.y);
      a3.z = fmaf(xv[j].z, w3.z, a3.z); a3.w = fmaf(xv[j].w, w3.w, a3.w);
    }
  }

  // ---- local top-2 over this lane's 4 experts (ascending index, strict >
  //      => lowest index wins ties, matching jax.lax.top_k) ----
  float m1 = -FLT_MAX, m2 = -FLT_MAX;
  int   i1 = E, i2 = E;
  {
    const float4 aa[4] = {a0, a1, a2, a3};
    #pragma unroll
    for (int e = 0; e < 4; ++e) {
      // horizontal sum in the proven order
      const float v = (aa[e].x + aa[e].y) + (aa[e].z + aa[e].w);
      const int idx = 4 * eq + e;
      const bool gt1 = v > m1;
      const bool gt2 = v > m2;
      m2 = gt1 ? m1 : (gt2 ? v : m2);
      i2 = gt1 ? i1 : (gt2 ? idx : i2);
      m1 = gt1 ? v : m1;
      i1 = gt1 ? idx : i1;
    }
  }

  // ---- butterfly merge across the 4 eq-groups (lane bits 4,5); selection
  //      is rounding-free; tie-break = lowest index (proven rounds 1-8) ----
  #pragma unroll
  for (int mask = 16; mask < 64; mask <<= 1) {
    const float om1 = __shfl_xor(m1, mask);
    const int   oi1 = __shfl_xor(i1, mask);
    const float om2 = __shfl_xor(m2, mask);
    const int   oi2 = __shfl_xor(i2, mask);
    const bool bwin = (om1 > m1) || (om1 == m1 && oi1 < i1);
    const float b1 = bwin ? om1 : m1; const int bi1 = bwin ? oi1 : i1;
    const float l1 = bwin ? m1 : om1; const int li1 = bwin ? i1 : oi1;
    const float b2 = bwin ? om2 : m2; const int bi2 = bwin ? oi2 : i2;
    const bool lwin = (l1 > b2) || (l1 == b2 && li1 < bi2);
    m1 = b1; i1 = bi1;
    m2 = lwin ? l1 : b2; i2 = lwin ? li1 : bi2;
  }

  if (eq == 0) {
    const float ex  = expf(m2 - m1);      // m2 <= m1 -> ex in (0,1]
    const float inv = 1.0f / (1.0f + ex);
    float2* outi = reinterpret_cast<float2*>(out);
    float2* outw = reinterpret_cast<float2*>(out + (size_t)N * 2);
    outi[row] = make_float2((float)i1, (float)i2);
    outw[row] = make_float2(inv, ex * inv);
  }
}

extern "C" void kernel_launch(void* const* d_in, const int* in_sizes, int n_in,
                              void* d_out, int out_size, void* d_ws, size_t ws_size,
                              hipStream_t stream) {
  const float* x = (const float*)d_in[0];
  const float* W = (const float*)d_in[1];
  float* out = (float*)d_out;
  const int N = in_sizes[0] / D;       // 131072
  const int grid = (N + RB - 1) / RB;  // 2048
  router_kernel<<<grid, BLOCK, 0, stream>>>(x, W, out, N);
}